// Round 1
// baseline (3394.743 us; speedup 1.0000x reference)
//
#include <hip/hip_runtime.h>
#include <math.h>

#define HH 1080
#define WW 1920
#define TOPK 32
#define MAXCAP 131072

struct GK { float w[25]; };

__constant__ int d_LA[24] = {1,1,2,3,1,5,6,1,8,9,10,8,12,13,0,0,15,16,11,11,14,14,22,19};
__constant__ int d_LB[24] = {0,2,3,4,5,6,7,8,9,10,11,12,13,14,15,16,17,18,24,22,21,19,23,20};
__constant__ int d_MC[24] = {30,14,16,18,22,24,26,0,6,2,4,8,10,12,32,34,36,38,50,46,44,40,48,42};

// ---- pass1: horizontal 25-tap conv; (H,W,26) interleaved -> (25,H,W) planar.
// threads: c = t%26 (c<25 active), yl = t/26 (yl<9). Register FIFO along x.
__global__ __launch_bounds__(256) void pass1(const float* __restrict__ in,
                                             float* __restrict__ xf, GK gk) {
  const int t = threadIdx.x;
  const int c = t % 26;
  const int yl = t / 26;
  if (yl >= 9 || c >= 25) return;
  const int y = blockIdx.y * 9 + yl;
  const int xs = blockIdx.x * 192;
  const float* row = in + (size_t)y * (WW * 26) + c;
  float* orow = xf + ((size_t)c * HH + y) * WW;
  float wb[25];
  // warmup: load xx = xs-12 .. xs+12 (symmetric map at left/right edges)
  #pragma unroll
  for (int u = 0; u < 25; ++u) {
    int xm = xs - 12 + u;
    if (xm < 0) xm = -1 - xm; else if (xm >= WW) xm = 2 * WW - 1 - xm;
    wb[u] = row[(size_t)xm * 26];
  }
  float4 ov;
  int xx = xs + 13;
  #pragma unroll 1
  for (int chunk = 0; chunk < 8; ++chunk) {
    #pragma unroll
    for (int u = 0; u < 25; ++u, ++xx) {
      if (xx > xs + 204) break;          // uniform
      int xm = xx;
      if (xm >= WW) xm = 2 * WW - 1 - xm; // main loop: only right edge possible
      float v = row[(size_t)xm * 26];     // prefetch next row value
      float f = 0.f;
      #pragma unroll
      for (int k = 0; k < 25; ++k) f += gk.w[k] * wb[(u + k) % 25];
      const int xc = xx - 13;
      const int q = xc & 3;
      if (q == 0) ov.x = f; else if (q == 1) ov.y = f; else if (q == 2) ov.z = f;
      else { ov.w = f; *(float4*)(orow + (xc - 3)) = ov; }
      wb[u] = v;                          // push AFTER conv consumed oldest
    }
  }
}

// ---- pass2: vertical 25-tap conv + peak mask + candidate push.
// One wave per (channel, yseg of 180 rows, 62-col strip). Lane l -> x = 62*strip-1+l.
// Lanes 0 and 63 are halo. x-neighbors via shfl, y-neighbors via delay regs.
__global__ __launch_bounds__(256) void pass2(const float* __restrict__ xf,
                                             const float* __restrict__ hm,
                                             float* __restrict__ cVal, int* __restrict__ cIdx,
                                             int* __restrict__ cnt, int cap, GK gk) {
  const int lane = threadIdx.x & 63;
  const int wid = blockIdx.x * 4 + (threadIdx.x >> 6);
  if (wid >= 25 * 6 * 31) return;
  const int strip = wid % 31;
  const int yseg = (wid / 31) % 6;
  const int c = wid / (31 * 6);
  const int x = strip * 62 - 1 + lane;
  const bool xok = (x >= 0) && (x < WW);
  const int xl = xok ? x : 0;
  const int g0 = yseg * 180;
  const float* plane = xf + (size_t)c * HH * WW + xl;
  float wb[25];
  #pragma unroll
  for (int u = 0; u < 25; ++u) {
    int ym2 = g0 - 13 + u;
    if (ym2 < 0) ym2 = -1 - ym2;          // symmetric (only top edge in warmup)
    wb[u] = plane[(size_t)ym2 * WW];
  }
  float f1 = 0.f, f2 = 0.f, fl1 = 0.f, fr1 = 0.f;
  int yy = g0 + 12;
  const int yend = g0 + 193;
  #pragma unroll 1
  for (int chunk = 0; chunk < 8; ++chunk) {
    #pragma unroll
    for (int u = 0; u < 25; ++u, ++yy) {
      if (yy > yend) break;               // uniform
      int ym2 = yy;
      if (ym2 >= HH) ym2 = 2 * HH - 1 - ym2;  // main loop: only bottom edge
      float v = plane[(size_t)ym2 * WW];  // prefetch
      float fn = 0.f;
      #pragma unroll
      for (int k = 0; k < 25; ++k) fn += gk.w[k] * wb[(u + k) % 25];
      const int yc = yy - 13;
      if (yc < 0 || yc >= HH || !xok) fn = 0.f;  // zero-pad semantics for mask
      const float fln = __shfl_up(fn, 1);
      const float frn = __shfl_down(fn, 1);
      const int ym = yy - 14;             // emit row
      bool peak = (ym >= g0) && (ym < g0 + 180) && (lane >= 1) && (lane <= 62) && xok
                  && (f1 > 0.1f) && (f1 >= f2) && (f1 >= fn) && (f1 >= fl1) && (f1 >= fr1);
      unsigned long long m = __ballot(peak);
      if (m) {
        const int nb = __popcll(m);
        const int leader = (int)__builtin_ctzll(m);
        int base = 0;
        if (lane == leader) base = atomicAdd(cnt + c, nb);
        base = __shfl(base, leader);
        if (peak) {
          const int pos = base + (int)__popcll(m & ((1ull << lane) - 1ull));
          if (pos < cap) {
            const int idx = ym * WW + x;
            cVal[(size_t)c * cap + pos] = hm[(size_t)idx * 26 + c]; // RAW value ranks
            cIdx[(size_t)c * cap + pos] = idx;
          }
        }
      }
      f2 = f1; f1 = fn; fl1 = fln; fr1 = frn;
      wb[u] = v;
    }
  }
}

// ---- top-32 per channel with jax top_k tie semantics (equal value -> lower index).
__global__ __launch_bounds__(256) void topk(float* __restrict__ cVal, const int* __restrict__ cIdx,
                                            const int* __restrict__ cnt, int cap,
                                            float* __restrict__ out) {
  __shared__ float sv[256];
  __shared__ int si[256];
  __shared__ int sp[256];
  const int c = blockIdx.x;
  const int t = threadIdx.x;
  int n = cnt[c]; if (n > cap) n = cap;
  float* v = cVal + (size_t)c * cap;
  const int* ix = cIdx + (size_t)c * cap;
  const int nk = n < TOPK ? n : TOPK;
  for (int r = 0; r < TOPK; ++r) {
    float bv = -1.f; int bi = 0x7fffffff; int bp = -1;
    if (r < nk) {
      for (int j = t; j < n; j += 256) {
        const float vv = v[j];
        if (vv > bv || (vv == bv && ix[j] < bi)) { bv = vv; bi = ix[j]; bp = j; }
      }
    }
    sv[t] = bv; si[t] = bi; sp[t] = bp;
    __syncthreads();
    for (int s = 128; s > 0; s >>= 1) {
      if (t < s) {
        const float o2 = sv[t + s];
        if (o2 > sv[t] || (o2 == sv[t] && si[t + s] < si[t])) {
          sv[t] = o2; si[t] = si[t + s]; sp[t] = sp[t + s];
        }
      }
      __syncthreads();
    }
    if (t == 0 && r < nk) {
      v[sp[0]] = -2.f;                     // exclude from later rounds
      const int idx = si[0];
      float* o = out + (c * TOPK + r) * 4;
      o[0] = (float)(idx % WW);
      o[1] = (float)(idx / WW);
      o[2] = sv[0];
      o[3] = 1.f;
    }
    __syncthreads();
  }
  // <32 peaks: jax fills with smallest non-peak indices (value NEG ties -> index order)
  if (t == 0 && nk < TOPK) {
    int fi = 0;
    for (int r = nk; r < TOPK; ++r) {
      for (;;) {
        bool mem = false;
        for (int q = 0; q < n; ++q) if (ix[q] == fi) { mem = true; break; }
        if (!mem) break;
        ++fi;
      }
      float* o = out + (c * TOPK + r) * 4;
      o[0] = (float)(fi % WW);
      o[1] = (float)(fi / WW);
      o[2] = 0.f;
      o[3] = 0.f;
      ++fi;
    }
  }
}

// ---- limb scoring: one thread per (limb, i, j) pair.
__global__ __launch_bounds__(1024) void limbk(const float* __restrict__ pk,
                                              const float* __restrict__ paf,
                                              float* __restrict__ out) {
  const int l = blockIdx.x;
  const int t = threadIdx.x;
  const int i = t >> 5, j = t & 31;
  const int a = d_LA[l], b = d_LB[l], cx = d_MC[l];
  const float* pa = pk + (a * TOPK + i) * 4;
  const float* pb = pk + (b * TOPK + j) * 4;
  const float xA = pa[0], yA = pa[1], sA = pa[2], vA = pa[3];
  const float xB = pb[0], yB = pb[1], sB = pb[2], vB = pb[3];
  const float dx = xB - xA, dy = yB - yA;
  float norm = sqrtf(dx * dx + dy * dy);
  norm = fmaxf(norm, 0.001f);
  const float ux = dx / norm, uy = dy / norm;
  float sum = 0.f; int cnum = 0;
  const float step = 1.0f / 9.0f;
  #pragma unroll
  for (int s = 0; s < 10; ++s) {
    const float tt = (float)s * step;
    const float fx = xA + tt * dx;
    const float fy = yA + tt * dy;
    int sx = (int)rintf(fx); sx = min(max(sx, 0), WW - 1);
    int sy = (int)rintf(fy); sy = min(max(sy, 0), HH - 1);
    const float* pp = paf + (size_t)(sy * WW + sx) * 52 + cx;
    const float vx = pp[0], vy = pp[1];
    const float sm = vx * ux + vy * uy;
    sum += sm;
    cnum += (sm > 0.05f) ? 1 : 0;
  }
  float prior = sum / 10.0f + fminf(540.0f / norm - 1.0f, 0.0f);
  const bool pv = (cnum > 8) && (prior > 0.0f) && (vA != 0.f) && (vB != 0.f);
  const float total = prior + sA + sB;
  float* o = out + 3200 + ((l * TOPK + i) * TOPK + j) * 3;
  o[0] = pv ? prior : 0.f;
  o[1] = pv ? total : 0.f;
  o[2] = pv ? 1.f : 0.f;
}

static GK make_gk() {
  GK g;
  double tmp[25], s = 0.0;
  for (int k = 0; k < 25; ++k) {
    const double d = (double)(k - 12) / 3.0;
    tmp[k] = exp(-0.5 * d * d);
    s += tmp[k];
  }
  for (int k = 0; k < 25; ++k) g.w[k] = (float)(tmp[k] / s);
  return g;
}

extern "C" void kernel_launch(void* const* d_in, const int* in_sizes, int n_in,
                              void* d_out, int out_size, void* d_ws, size_t ws_size,
                              hipStream_t stream) {
  const float* hm = (const float*)d_in[0];
  const float* paf = (const float*)d_in[1];
  float* out = (float*)d_out;
  char* ws = (char*)d_ws;
  int* cnt = (int*)ws;
  float* xf = (float*)(ws + 256);
  const size_t xfB = (size_t)25 * HH * WW * sizeof(float);
  const size_t off = 256 + xfB;
  const size_t rem = (ws_size > off) ? (ws_size - off) : 0;
  size_t capz = rem / (25 * 8);
  int cap = capz > MAXCAP ? MAXCAP : (int)capz;
  if (cap < 1) cap = 1;
  float* cVal = (float*)(ws + off);
  int* cIdx = (int*)(ws + off + (size_t)25 * cap * sizeof(float));
  const GK gk = make_gk();
  hipMemsetAsync(cnt, 0, 25 * sizeof(int), stream);
  pass1<<<dim3(10, 120), 256, 0, stream>>>(hm, xf, gk);
  const int nw = 25 * 6 * 31;
  pass2<<<(nw + 3) / 4, 256, 0, stream>>>(xf, hm, cVal, cIdx, cnt, cap, gk);
  topk<<<25, 256, 0, stream>>>(cVal, cIdx, cnt, cap, out);
  limbk<<<24, 1024, 0, stream>>>(out, paf, out);
}

// Round 2
// 1501.448 us; speedup vs baseline: 2.2610x; 2.2610x over previous
//
#include <hip/hip_runtime.h>
#include <math.h>

#define HH 1080
#define WW 1920
#define TOPK 32
#define NWAVES (25*6*31)   // 4650 waves in pass2
#define NW_PER_C (6*31)    // 186 wave-regions per channel
#define CAPW_MAX 512

struct GK { float w[25]; };

__constant__ int d_LA[24] = {1,1,2,3,1,5,6,1,8,9,10,8,12,13,0,0,15,16,11,11,14,14,22,19};
__constant__ int d_LB[24] = {0,2,3,4,5,6,7,8,9,10,11,12,13,14,15,16,17,18,24,22,21,19,23,20};
__constant__ int d_MC[24] = {30,14,16,18,22,24,26,0,6,2,4,8,10,12,32,34,36,38,50,46,44,40,48,42};

// ---- pass1: horizontal 25-tap conv; (H,W,26) interleaved -> (25,H,W) planar.
__global__ __launch_bounds__(256) void pass1(const float* __restrict__ in,
                                             float* __restrict__ xf, GK gk) {
  const int t = threadIdx.x;
  const int c = t % 26;
  const int yl = t / 26;
  if (yl >= 9 || c >= 25) return;
  const int y = blockIdx.y * 9 + yl;
  const int xs = blockIdx.x * 192;
  const float* row = in + (size_t)y * (WW * 26) + c;
  float* orow = xf + ((size_t)c * HH + y) * WW;
  float wb[25];
  #pragma unroll
  for (int u = 0; u < 25; ++u) {
    int xm = xs - 12 + u;
    if (xm < 0) xm = -1 - xm; else if (xm >= WW) xm = 2 * WW - 1 - xm;
    wb[u] = row[(size_t)xm * 26];
  }
  float4 ov;
  int xx = xs + 13;
  #pragma unroll 1
  for (int chunk = 0; chunk < 8; ++chunk) {
    #pragma unroll
    for (int u = 0; u < 25; ++u, ++xx) {
      if (xx > xs + 204) break;
      int xm = xx;
      if (xm >= WW) xm = 2 * WW - 1 - xm;
      float v = row[(size_t)xm * 26];
      float f = 0.f;
      #pragma unroll
      for (int k = 0; k < 25; ++k) f += gk.w[k] * wb[(u + k) % 25];
      const int xc = xx - 13;
      const int q = xc & 3;
      if (q == 0) ov.x = f; else if (q == 1) ov.y = f; else if (q == 2) ov.z = f;
      else { ov.w = f; *(float4*)(orow + (xc - 3)) = ov; }
      wb[u] = v;
    }
  }
}

// ---- pass2: vertical 25-tap conv + peak mask; candidates go to WAVE-PRIVATE
// regions (no global atomics). Stores only the flat pixel index (4 B).
__global__ __launch_bounds__(256) void pass2(const float* __restrict__ xf,
                                             int* __restrict__ cIdx,
                                             int* __restrict__ cnts, int capw, GK gk) {
  const int lane = threadIdx.x & 63;
  const int wid = blockIdx.x * 4 + (threadIdx.x >> 6);
  if (wid >= NWAVES) return;
  const int strip = wid % 31;
  const int yseg = (wid / 31) % 6;
  const int c = wid / (31 * 6);
  const int x = strip * 62 - 1 + lane;
  const bool xok = (x >= 0) && (x < WW);
  const int xl = xok ? x : 0;
  const int g0 = yseg * 180;
  const float* plane = xf + (size_t)c * HH * WW + xl;
  int* reg = cIdx + (size_t)wid * capw;
  float wb[25];
  #pragma unroll
  for (int u = 0; u < 25; ++u) {
    int ym2 = g0 - 13 + u;
    if (ym2 < 0) ym2 = -1 - ym2;
    wb[u] = plane[(size_t)ym2 * WW];
  }
  float f1 = 0.f, f2 = 0.f, fl1 = 0.f, fr1 = 0.f;
  int pcnt = 0;
  int yy = g0 + 12;
  const int yend = g0 + 193;
  #pragma unroll 1
  for (int chunk = 0; chunk < 8; ++chunk) {
    #pragma unroll
    for (int u = 0; u < 25; ++u, ++yy) {
      if (yy > yend) break;
      int ym2 = yy;
      if (ym2 >= HH) ym2 = 2 * HH - 1 - ym2;
      float v = plane[(size_t)ym2 * WW];
      float fn = 0.f;
      #pragma unroll
      for (int k = 0; k < 25; ++k) fn += gk.w[k] * wb[(u + k) % 25];
      const int yc = yy - 13;
      if (yc < 0 || yc >= HH || !xok) fn = 0.f;
      const float fln = __shfl_up(fn, 1);
      const float frn = __shfl_down(fn, 1);
      const int ym = yy - 14;
      bool peak = (ym >= g0) && (ym < g0 + 180) && (lane >= 1) && (lane <= 62) && xok
                  && (f1 > 0.1f) && (f1 >= f2) && (f1 >= fn) && (f1 >= fl1) && (f1 >= fr1);
      unsigned long long m = __ballot(peak);
      if (peak) {
        const int pos = pcnt + (int)__popcll(m & ((1ull << lane) - 1ull));
        if (pos < capw) reg[pos] = ym * WW + x;
      }
      pcnt += (int)__popcll(m);
      f2 = f1; f1 = fn; fl1 = fln; fr1 = frn;
      wb[u] = v;
    }
  }
  if (lane == 0) cnts[wid] = pcnt > capw ? capw : pcnt;
}

// ---- select: per-channel top-32 via value histogram + exact rank of survivors.
// jax top_k tie semantics via key = (value_bits<<32) | (~idx): desc value, asc idx.
__global__ __launch_bounds__(256) void selk(const int* __restrict__ cIdx,
                                            const int* __restrict__ cnts,
                                            const float* __restrict__ hm,
                                            int capw, float* __restrict__ out) {
  __shared__ unsigned int hist[2048];
  __shared__ unsigned long long scol[1024];
  __shared__ unsigned int ncol;
  __shared__ int tb_s, ntot_s;
  const int c = blockIdx.x, t = threadIdx.x;
  for (int b = t; b < 2048; b += 256) hist[b] = 0;
  if (t == 0) ncol = 0;
  __syncthreads();
  for (int r = 0; r < NW_PER_C; ++r) {
    const int wid = c * NW_PER_C + r;
    int n = cnts[wid]; if (n > capw) n = capw;
    const int* reg = cIdx + (size_t)wid * capw;
    for (int j = t; j < n; j += 256) {
      const float v = hm[(size_t)reg[j] * 26 + c];
      int b = (int)(v * 2048.0f);
      b = b < 0 ? 0 : (b > 2047 ? 2047 : b);
      atomicAdd(&hist[b], 1u);
    }
  }
  __syncthreads();
  if (t == 0) {
    int cum = 0, tb = 0;
    for (int b = 2047; b >= 0; --b) { cum += (int)hist[b]; if (cum >= TOPK) { tb = b; break; } }
    tb_s = tb;
    int ntot = 0;
    for (int r = 0; r < NW_PER_C; ++r) { int n = cnts[c * NW_PER_C + r]; if (n > capw) n = capw; ntot += n; }
    ntot_s = ntot;
  }
  __syncthreads();
  const int tb = tb_s;
  for (int r = 0; r < NW_PER_C; ++r) {
    const int wid = c * NW_PER_C + r;
    int n = cnts[wid]; if (n > capw) n = capw;
    const int* reg = cIdx + (size_t)wid * capw;
    for (int j = t; j < n; j += 256) {
      const int idx = reg[j];
      const float v = hm[(size_t)idx * 26 + c];
      int b = (int)(v * 2048.0f);
      b = b < 0 ? 0 : (b > 2047 ? 2047 : b);
      if (b >= tb) {
        const unsigned int p = atomicAdd(&ncol, 1u);
        if (p < 1024)
          scol[p] = ((unsigned long long)__float_as_uint(v) << 32)
                  | (unsigned long long)(0xFFFFFFFFu - (unsigned int)idx);
      }
    }
  }
  __syncthreads();
  int n = (int)ncol; if (n > 1024) n = 1024;
  for (int i = t; i < n; i += 256) {
    const unsigned long long ki = scol[i];
    int rank = 0;
    for (int j = 0; j < n; ++j) rank += (scol[j] > ki) ? 1 : 0;
    if (rank < TOPK) {
      const int idx = (int)(0xFFFFFFFFu - (unsigned int)ki);
      float* o = out + (c * TOPK + rank) * 4;
      o[0] = (float)(idx % WW);
      o[1] = (float)(idx / WW);
      o[2] = __uint_as_float((unsigned int)(ki >> 32));
      o[3] = 1.0f;
    }
  }
  __syncthreads();
  if (t == 0 && ntot_s < TOPK) {   // filler: smallest non-peak flat indices
    int fi = 0;
    for (int r2 = ntot_s; r2 < TOPK; ++r2) {
      for (;;) {
        bool mem = false;
        for (int q = 0; q < n; ++q)
          if ((int)(0xFFFFFFFFu - (unsigned int)scol[q]) == fi) { mem = true; break; }
        if (!mem) break;
        ++fi;
      }
      float* o = out + (c * TOPK + r2) * 4;
      o[0] = (float)(fi % WW);
      o[1] = (float)(fi / WW);
      o[2] = 0.f;
      o[3] = 0.f;
      ++fi;
    }
  }
}

// ---- limb scoring: one thread per (limb, i, j) pair.
__global__ __launch_bounds__(1024) void limbk(const float* __restrict__ pk,
                                              const float* __restrict__ paf,
                                              float* __restrict__ out) {
  const int l = blockIdx.x;
  const int t = threadIdx.x;
  const int i = t >> 5, j = t & 31;
  const int a = d_LA[l], b = d_LB[l], cx = d_MC[l];
  const float* pa = pk + (a * TOPK + i) * 4;
  const float* pb = pk + (b * TOPK + j) * 4;
  const float xA = pa[0], yA = pa[1], sA = pa[2], vA = pa[3];
  const float xB = pb[0], yB = pb[1], sB = pb[2], vB = pb[3];
  const float dx = xB - xA, dy = yB - yA;
  float norm = sqrtf(dx * dx + dy * dy);
  norm = fmaxf(norm, 0.001f);
  const float ux = dx / norm, uy = dy / norm;
  float sum = 0.f; int cnum = 0;
  const float step = 1.0f / 9.0f;
  #pragma unroll
  for (int s = 0; s < 10; ++s) {
    const float tt = (float)s * step;
    const float fx = xA + tt * dx;
    const float fy = yA + tt * dy;
    int sx = (int)rintf(fx); sx = min(max(sx, 0), WW - 1);
    int sy = (int)rintf(fy); sy = min(max(sy, 0), HH - 1);
    const float* pp = paf + (size_t)(sy * WW + sx) * 52 + cx;
    const float vx = pp[0], vy = pp[1];
    const float sm = vx * ux + vy * uy;
    sum += sm;
    cnum += (sm > 0.05f) ? 1 : 0;
  }
  float prior = sum / 10.0f + fminf(540.0f / norm - 1.0f, 0.0f);
  const bool pv = (cnum > 8) && (prior > 0.0f) && (vA != 0.f) && (vB != 0.f);
  const float total = prior + sA + sB;
  float* o = out + 3200 + ((l * TOPK + i) * TOPK + j) * 3;
  o[0] = pv ? prior : 0.f;
  o[1] = pv ? total : 0.f;
  o[2] = pv ? 1.f : 0.f;
}

static GK make_gk() {
  GK g;
  double tmp[25], s = 0.0;
  for (int k = 0; k < 25; ++k) {
    const double d = (double)(k - 12) / 3.0;
    tmp[k] = exp(-0.5 * d * d);
    s += tmp[k];
  }
  for (int k = 0; k < 25; ++k) g.w[k] = (float)(tmp[k] / s);
  return g;
}

extern "C" void kernel_launch(void* const* d_in, const int* in_sizes, int n_in,
                              void* d_out, int out_size, void* d_ws, size_t ws_size,
                              hipStream_t stream) {
  const float* hm = (const float*)d_in[0];
  const float* paf = (const float*)d_in[1];
  float* out = (float*)d_out;
  char* ws = (char*)d_ws;
  int* cnts = (int*)ws;                              // NWAVES ints
  float* xf = (float*)(ws + 32768);
  const size_t xfB = (size_t)25 * HH * WW * sizeof(float);
  const size_t off = 32768 + xfB;
  const size_t avail = (ws_size > off) ? (ws_size - off) : 0;
  size_t capz = avail / ((size_t)NWAVES * sizeof(int));
  int capw = capz > CAPW_MAX ? CAPW_MAX : (int)capz;
  if (capw < 1) capw = 1;
  int* cIdx = (int*)(ws + off);
  const GK gk = make_gk();
  pass1<<<dim3(10, 120), 256, 0, stream>>>(hm, xf, gk);
  pass2<<<(NWAVES + 3) / 4, 256, 0, stream>>>(xf, cIdx, cnts, capw, gk);
  selk<<<25, 256, 0, stream>>>(cIdx, cnts, hm, capw, out);
  limbk<<<24, 1024, 0, stream>>>(out, paf, out);
}

// Round 6
// 993.289 us; speedup vs baseline: 3.4177x; 1.5116x over previous
//
#include <hip/hip_runtime.h>
#include <math.h>

#define HH 1080
#define WW 1920
#define TOPK 32
#define TILE_X 240
#define SPAN (TILE_X + 24)      // 264
#define NSEG 9                  // 120 rows per segment
#define NSTRIP 31               // 62 cols per strip
#define NW_PER_C (NSEG * NSTRIP)        // 279
#define NWAVES (25 * NW_PER_C)          // 6975
#define CAPW 256

struct GK { float w[25]; };

__constant__ int d_LA[24] = {1,1,2,3,1,5,6,1,8,9,10,8,12,13,0,0,15,16,11,11,14,14,22,19};
__constant__ int d_LB[24] = {0,2,3,4,5,6,7,8,9,10,11,12,13,14,15,16,17,18,24,22,21,19,23,20};
__constant__ int d_MC[24] = {30,14,16,18,22,24,26,0,6,2,4,8,10,12,32,34,36,38,50,46,44,40,48,42};

// ---- pass1: horizontal 25-tap conv via LDS row tile.
// Block = (x-tile of 240, one y row). Lanes = consecutive x -> coalesced stores.
__global__ __launch_bounds__(256) void pass1(const float* __restrict__ in,
                                             float* __restrict__ xf, GK gk) {
  __shared__ float s[SPAN * 27];
  const int t = threadIdx.x;
  const int y = blockIdx.y;
  const int xs = blockIdx.x * TILE_X;
  const float* row = in + (size_t)y * (WW * 26);
  for (int f = t; f < SPAN * 26; f += 256) {
    const int xi = f / 26;
    const int c = f - xi * 26;
    int xm = xs - 12 + xi;
    if (xm < 0) xm = -1 - xm; else if (xm >= WW) xm = 2 * WW - 1 - xm;
    s[xi * 27 + c] = row[(size_t)xm * 26 + c];
  }
  __syncthreads();
  for (int f = t; f < TILE_X * 25; f += 256) {
    const int c = f / TILE_X;
    const int xl = f - c * TILE_X;
    float acc = 0.f;
    #pragma unroll
    for (int k = 0; k < 25; ++k) acc += gk.w[k] * s[(xl + k) * 27 + c];
    xf[((size_t)c * HH + y) * WW + xs + xl] = acc;
  }
}

// ---- pass2: vertical 25-tap conv + peak mask; wave-private candidate regions.
// Stores flat index (+ raw value unless gather mode).
__global__ __launch_bounds__(256) void pass2(const float* __restrict__ xf,
                                             const float* __restrict__ hm,
                                             int* __restrict__ cIdx,
                                             float* __restrict__ cVal,
                                             int* __restrict__ cnts,
                                             int capw, int gather, GK gk) {
  const int lane = threadIdx.x & 63;
  const int wid = blockIdx.x * 4 + (threadIdx.x >> 6);
  if (wid >= NWAVES) return;
  const int strip = wid % NSTRIP;
  const int yseg = (wid / NSTRIP) % NSEG;
  const int c = wid / NW_PER_C;
  const int x = strip * 62 - 1 + lane;
  const bool xok = (x >= 0) && (x < WW);
  const int xl = xok ? x : 0;
  const int g0 = yseg * 120;
  const float* plane = xf + (size_t)c * HH * WW + xl;
  int* regI = cIdx + (size_t)wid * capw;
  float* regV = cVal + (size_t)wid * capw;
  float wb[25];
  #pragma unroll
  for (int u = 0; u < 25; ++u) {
    int ym2 = g0 - 13 + u;
    if (ym2 < 0) ym2 = -1 - ym2;
    wb[u] = plane[(size_t)ym2 * WW];
  }
  float f1 = 0.f, f2 = 0.f, fl1 = 0.f, fr1 = 0.f;
  int pcnt = 0;
  int yy = g0 + 12;
  const int yend = g0 + 133;
  #pragma unroll 1
  for (int chunk = 0; chunk < 5; ++chunk) {
    #pragma unroll
    for (int u = 0; u < 25; ++u, ++yy) {
      if (yy > yend) break;
      int ym2 = yy;
      if (ym2 >= HH) ym2 = 2 * HH - 1 - ym2;
      float v = plane[(size_t)ym2 * WW];
      float fn = 0.f;
      #pragma unroll
      for (int k = 0; k < 25; ++k) fn += gk.w[k] * wb[(u + k) % 25];
      const int yc = yy - 13;
      if (yc < 0 || yc >= HH || !xok) fn = 0.f;
      const float fln = __shfl_up(fn, 1);
      const float frn = __shfl_down(fn, 1);
      const int ym = yy - 14;
      bool peak = (ym >= g0) && (ym < g0 + 120) && (lane >= 1) && (lane <= 62) && xok
                  && (f1 > 0.1f) && (f1 >= f2) && (f1 >= fn) && (f1 >= fl1) && (f1 >= fr1);
      unsigned long long m = __ballot(peak);
      if (peak) {
        const int pos = pcnt + (int)__popcll(m & ((1ull << lane) - 1ull));
        if (pos < capw) {
          const int idx = ym * WW + x;
          regI[pos] = idx;
          if (!gather) regV[pos] = hm[(size_t)idx * 26 + c];
        }
      }
      pcnt += (int)__popcll(m);
      f2 = f1; f1 = fn; fl1 = fln; fr1 = frn;
      wb[u] = v;
    }
  }
  if (lane == 0) cnts[wid] = pcnt > capw ? capw : pcnt;
}

// ---- selk: per-channel top-32. 8 waves independently sweep region subsets:
// histogram -> threshold bin -> collect survivors -> exact O(n^2) rank.
// jax tie semantics: key = (value_bits<<32) | ~idx  (desc value, asc idx).
__global__ __launch_bounds__(512) void selk(const int* __restrict__ cIdx,
                                            const float* __restrict__ cVal,
                                            const int* __restrict__ cnts,
                                            const float* __restrict__ hm,
                                            int capw, int gather,
                                            float* __restrict__ out) {
  __shared__ unsigned int hist[2048];
  __shared__ unsigned int csum[512];
  __shared__ unsigned long long scol[1024];
  __shared__ unsigned int ncol;
  __shared__ unsigned int ntot_s;
  __shared__ int tb_s;
  const int c = blockIdx.x, t = threadIdx.x;
  const int wv = t >> 6, lane = t & 63;
  for (int b = t; b < 2048; b += 512) hist[b] = 0;
  if (t == 0) { ncol = 0; ntot_s = 0; }
  __syncthreads();
  unsigned myn = 0;
  for (int r = wv; r < NW_PER_C; r += 8) {
    const int wid = c * NW_PER_C + r;
    int n = cnts[wid]; if (n > capw) n = capw;
    if (lane == 0) myn += (unsigned)n;
    const int* rI = cIdx + (size_t)wid * capw;
    const float* rV = cVal + (size_t)wid * capw;
    for (int j = lane; j < n; j += 64) {
      const float v = gather ? hm[(size_t)rI[j] * 26 + c] : rV[j];
      int b = (int)(v * 2048.0f);
      b = b < 0 ? 0 : (b > 2047 ? 2047 : b);
      atomicAdd(&hist[b], 1u);
    }
  }
  if (lane == 0) atomicAdd(&ntot_s, myn);
  __syncthreads();
  const unsigned s4 = hist[t * 4] + hist[t * 4 + 1] + hist[t * 4 + 2] + hist[t * 4 + 3];
  csum[t] = s4;
  __syncthreads();
  if (t == 0) {
    int cum = 0, tb = 0;
    for (int ch = 511; ch >= 0; --ch) {
      if (cum + (int)csum[ch] >= TOPK) {
        for (int b = ch * 4 + 3; b >= ch * 4; --b) {
          cum += (int)hist[b];
          if (cum >= TOPK) { tb = b; break; }
        }
        break;
      }
      cum += (int)csum[ch];
    }
    tb_s = tb;
  }
  __syncthreads();
  const int tb = tb_s;
  for (int r = wv; r < NW_PER_C; r += 8) {
    const int wid = c * NW_PER_C + r;
    int n = cnts[wid]; if (n > capw) n = capw;
    const int* rI = cIdx + (size_t)wid * capw;
    const float* rV = cVal + (size_t)wid * capw;
    for (int j = lane; j < n; j += 64) {
      const int idx = rI[j];
      const float v = gather ? hm[(size_t)idx * 26 + c] : rV[j];
      int b = (int)(v * 2048.0f);
      b = b < 0 ? 0 : (b > 2047 ? 2047 : b);
      if (b >= tb) {
        const unsigned p = atomicAdd(&ncol, 1u);
        if (p < 1024)
          scol[p] = ((unsigned long long)__float_as_uint(v) << 32)
                  | (unsigned long long)(0xFFFFFFFFu - (unsigned)idx);
      }
    }
  }
  __syncthreads();
  int n = (int)ncol; if (n > 1024) n = 1024;
  for (int i = t; i < n; i += 512) {
    const unsigned long long ki = scol[i];
    int rank = 0;
    for (int j = 0; j < n; ++j) rank += (scol[j] > ki) ? 1 : 0;
    if (rank < TOPK) {
      const int idx = (int)(0xFFFFFFFFu - (unsigned)ki);
      float* o = out + (c * TOPK + rank) * 4;
      o[0] = (float)(idx % WW);
      o[1] = (float)(idx / WW);
      o[2] = __uint_as_float((unsigned)(ki >> 32));
      o[3] = 1.0f;
    }
  }
  __syncthreads();
  if (t == 0 && (int)ntot_s < TOPK) {   // filler: smallest non-peak flat indices
    const int nt = (int)ntot_s;
    int fi = 0;
    for (int r2 = nt; r2 < TOPK; ++r2) {
      for (;;) {
        bool mem = false;
        for (int q = 0; q < n; ++q)
          if ((int)(0xFFFFFFFFu - (unsigned)scol[q]) == fi) { mem = true; break; }
        if (!mem) break;
        ++fi;
      }
      float* o = out + (c * TOPK + r2) * 4;
      o[0] = (float)(fi % WW);
      o[1] = (float)(fi / WW);
      o[2] = 0.f;
      o[3] = 0.f;
      ++fi;
    }
  }
}

// ---- limb scoring: one thread per (limb, i, j) pair.
__global__ __launch_bounds__(1024) void limbk(const float* __restrict__ pk,
                                              const float* __restrict__ paf,
                                              float* __restrict__ out) {
  const int l = blockIdx.x;
  const int t = threadIdx.x;
  const int i = t >> 5, j = t & 31;
  const int a = d_LA[l], b = d_LB[l], cx = d_MC[l];
  const float* pa = pk + (a * TOPK + i) * 4;
  const float* pb = pk + (b * TOPK + j) * 4;
  const float xA = pa[0], yA = pa[1], sA = pa[2], vA = pa[3];
  const float xB = pb[0], yB = pb[1], sB = pb[2], vB = pb[3];
  const float dx = xB - xA, dy = yB - yA;
  float norm = sqrtf(dx * dx + dy * dy);
  norm = fmaxf(norm, 0.001f);
  const float ux = dx / norm, uy = dy / norm;
  float sum = 0.f; int cnum = 0;
  const float step = 1.0f / 9.0f;
  #pragma unroll
  for (int s = 0; s < 10; ++s) {
    const float tt = (float)s * step;
    const float fx = xA + tt * dx;
    const float fy = yA + tt * dy;
    int sx = (int)rintf(fx); sx = min(max(sx, 0), WW - 1);
    int sy = (int)rintf(fy); sy = min(max(sy, 0), HH - 1);
    const float* pp = paf + (size_t)(sy * WW + sx) * 52 + cx;
    const float vx = pp[0], vy = pp[1];
    const float sm = vx * ux + vy * uy;
    sum += sm;
    cnum += (sm > 0.05f) ? 1 : 0;
  }
  float prior = sum / 10.0f + fminf(540.0f / norm - 1.0f, 0.0f);
  const bool pv = (cnum > 8) && (prior > 0.0f) && (vA != 0.f) && (vB != 0.f);
  const float total = prior + sA + sB;
  float* o = out + 3200 + ((l * TOPK + i) * TOPK + j) * 3;
  o[0] = pv ? prior : 0.f;
  o[1] = pv ? total : 0.f;
  o[2] = pv ? 1.f : 0.f;
}

static GK make_gk() {
  GK g;
  double tmp[25], s = 0.0;
  for (int k = 0; k < 25; ++k) {
    const double d = (double)(k - 12) / 3.0;
    tmp[k] = exp(-0.5 * d * d);
    s += tmp[k];
  }
  for (int k = 0; k < 25; ++k) g.w[k] = (float)(tmp[k] / s);
  return g;
}

extern "C" void kernel_launch(void* const* d_in, const int* in_sizes, int n_in,
                              void* d_out, int out_size, void* d_ws, size_t ws_size,
                              hipStream_t stream) {
  const float* hm = (const float*)d_in[0];
  const float* paf = (const float*)d_in[1];
  float* out = (float*)d_out;
  char* ws = (char*)d_ws;
  int* cnts = (int*)ws;                           // NWAVES ints (all written by pass2)
  float* xf = (float*)(ws + 32768);
  const size_t xfB = (size_t)25 * HH * WW * sizeof(float);
  const size_t off = 32768 + xfB;
  const size_t avail = (ws_size > off) ? (ws_size - off) : 0;
  int capw, gather;
  const size_t cap8 = avail / ((size_t)NWAVES * 8);
  if (cap8 >= 224) {                              // val+idx mode
    capw = cap8 > CAPW ? CAPW : (int)cap8;
    gather = 0;
  } else {                                        // idx-only fallback (selk gathers)
    size_t cap4 = avail / ((size_t)NWAVES * 4);
    capw = cap4 > CAPW ? CAPW : (int)cap4;
    if (capw < 1) capw = 1;
    gather = 1;
  }
  int* cIdx = (int*)(ws + off);
  float* cVal = (float*)(ws + off + (size_t)NWAVES * capw * sizeof(int));
  const GK gk = make_gk();
  pass1<<<dim3(WW / TILE_X, HH), 256, 0, stream>>>(hm, xf, gk);
  pass2<<<(NWAVES + 3) / 4, 256, 0, stream>>>(xf, hm, cIdx, cVal, cnts, capw, gather, gk);
  selk<<<25, 512, 0, stream>>>(cIdx, cVal, cnts, hm, capw, gather, out);
  limbk<<<24, 1024, 0, stream>>>(out, paf, out);
}